// Round 12
// baseline (196.271 us; speedup 1.0000x reference)
//
#include <hip/hip_runtime.h>
#include <math.h>

#define BATCH 2048
#define TLEN  1440
#define CL0   48     // chunk 0 length (>= ENC_LEN=48, covers teacher forcing)
#define CLS   12     // small-chunk length for t >= 48
#define NS    116    // (TLEN - CL0) / CLS
#define NCC   117    // total chunks = 1 + NS
#define ER    128    // e rows per batch (117 used; padded for lane reads)
#define TB    64     // b-tile
#define TT    48     // t-tile (= 4 small chunks = 1 forced chunk)
#define LP    65     // padded LDS row stride

// ---- workspace layout (float offsets) ----
// e: [BATCH][ER][8]  (k2a scatter-writes; k2sc reads lane-consecutive = coalesced)
#define E_OFF    0
#define WS_FLOATS (E_OFF + BATCH*ER*8)

__device__ __forceinline__ float sp_precise(float x) { return log1pf(expf(x)); }

// Derived scalar params — expression sequence identical to the r7-proven k0.
struct Prm {
  float P[5], M[5], Q[5], K[5];
  float AZ, dtczw, dtcz, cInt, cHv, cDir;
  float r[5], cc[5];
};
__device__ __forceinline__ Prm make_prm(
    const float* __restrict__ rcR, const float* __restrict__ rcC,
    const float* __restrict__ winR, const float* __restrict__ hvg,
    const float* __restrict__ ing, const float* __restrict__ dg,
    const float* __restrict__ aw, const float* __restrict__ ar,
    const float* __restrict__ zc) {
  Prm p;
  #pragma unroll
  for (int j = 0; j < 5; ++j) { p.r[j] = sp_precise(rcR[j]) * 0.1f; p.cc[j] = sp_precise(rcC[j]) * 1e-5f; }
  float w  = (sp_precise(winR[0]) + sp_precise(winR[1])) * 0.5f;
  float cz = sp_precise(zc[0]) * 1e-5f;
  float aW = sp_precise(aw[0]) * 0.5f, aR = sp_precise(ar[0]) * 0.5f;
  float dtcz = 900.f * cz;
  float rsum = 0.f;
  #pragma unroll
  for (int j = 0; j < 5; ++j) {
    float P = 900.f * p.r[j] * p.cc[j];
    p.P[j] = P;
    p.M[j] = 1.f - 2.f * P;
    p.Q[j] = 900.f * p.cc[j] * ((j < 4) ? aW : aR);
    p.K[j] = dtcz * p.r[j];
    rsum += p.r[j];
  }
  p.AZ    = 1.f - dtcz * (w + rsum);
  p.dtczw = dtcz * w;
  p.dtcz  = dtcz;
  p.cInt  = sp_precise(ing[0]) * 0.1f;
  p.cHv   = sp_precise(hvg[0]) * 0.1f;
  p.cDir  = sp_precise(dg[0])  * 0.5f;
  return p;
}

// ============ K2a: tiled fused MLP + scan (r11-proven; params inlined) ============
__global__ __launch_bounds__(256) void k2a_scan(const float* __restrict__ X,
    const float* __restrict__ rcR, const float* __restrict__ rcC,
    const float* __restrict__ winR, const float* __restrict__ hvg,
    const float* __restrict__ W1, const float* __restrict__ B1,
    const float* __restrict__ W2, const float* __restrict__ B2,
    const float* __restrict__ ing, const float* __restrict__ dg,
    const float* __restrict__ aw, const float* __restrict__ ar,
    const float* __restrict__ zc,
    float* __restrict__ out, float* __restrict__ ws) {
  __shared__ float sTa[TT * LP], sSo[TT * LP], sU[TT * LP], sTz[TT * LP];
  int tile   = blockIdx.x;
  int tile_t = tile >> 5;          // 0..29
  int tile_b = tile & 31;          // 0..31
  int t0 = tile_t * TT, b0 = tile_b * TB;
  Prm pp = make_prm(rcR, rcC, winR, hvg, ing, dg, aw, ar, zc);
  float P0 = pp.P[0], P1 = pp.P[1], P2 = pp.P[2], P3 = pp.P[3], P4 = pp.P[4];
  float M0 = pp.M[0], M1 = pp.M[1], M2 = pp.M[2], M3 = pp.M[3], M4 = pp.M[4];
  float Q0 = pp.Q[0], Q1 = pp.Q[1], Q2 = pp.Q[2], Q3 = pp.Q[3], Q4 = pp.Q[4];
  float K0 = pp.K[0], K1 = pp.K[1], K2 = pp.K[2], K3 = pp.K[3], K4 = pp.K[4];
  float AZ = pp.AZ, dtczw = pp.dtczw, dtcz = pp.dtcz;
  float cInt = pp.cInt, cHv = pp.cHv, cDir = pp.cDir;
  float b2v = B2[0];

  // ---- Phase A: 12 elems/thread, lane-consecutive in t (coalesced scalar loads) ----
  #pragma unroll 4
  for (int r = 0; r < (TB * TT) / 256; ++r) {
    int e  = threadIdx.x + 256 * r;
    int bl = e / TT;
    int tt = e - bl * TT;
    const float* x = X + ((size_t)(b0 + bl) * TLEN + (t0 + tt)) * 7;
    float x0 = x[0], ta = x[1], so = x[2], x3 = x[3], x4 = x[4], x5 = x[5], hv = x[6];
    float acc = b2v;
    #pragma unroll
    for (int h = 0; h < 32; ++h) {
      float z = fmaf(W1[2 * h], x3, fmaf(W1[2 * h + 1], x4, B1[h]));
      acc = fmaf(W2[h], fmaxf(z, 0.f), acc);
    }
    float sch = __frcp_rn(1.f + __expf(-acc)) + x5;
    float q = fmaf(cInt, sch, fmaf(cHv, hv, cDir * so));
    float u = fmaf(dtczw, ta, dtcz * q);
    sTa[tt * LP + bl] = ta;
    sSo[tt * LP + bl] = so;
    sU [tt * LP + bl] = u;
    sTz[tt * LP + bl] = x0;   // tz_gt staging (tile 0 forcing); overwritten by outputs
  }
  __syncthreads();

  // ---- Phase B: per-wave chunk scans from LDS ----
  int w = threadIdx.x >> 6, l = threadIdx.x & 63;
  int b = b0 + l;
  bool tile0 = (tile_t == 0);
  int c, kbeg, ksteps;
  if (tile0) { c = 0; kbeg = 0; ksteps = (w == 0) ? CL0 : 0; }
  else       { c = 1 + (tile_t - 1) * 4 + w; kbeg = w * CLS; ksteps = CLS; }
  float Tz = 0.f, T0 = 0.f, T1 = 0.f, T2 = 0.f, T3 = 0.f, T4 = 0.f;
  if (tile0) {
    float tz0 = sTz[l], ta0 = sTa[l];
    Tz = tz0;
    float tm = fmaf(0.7f, tz0, 0.3f * ta0);
    T0 = T1 = T2 = T3 = T4 = tm;
  }
  for (int k = kbeg; k < kbeg + ksteps; ++k) {
    float ta = sTa[k * LP + l], so = sSo[k * LP + l], u = sU[k * LP + l];
    float d = fmaf(K0, T0, u);
    d = fmaf(K1, T1, d); d = fmaf(K2, T2, d); d = fmaf(K3, T3, d); d = fmaf(K4, T4, d);
    float tzn = fmaf(AZ, Tz, d);
    T0 = fmaf(M0, T0, fmaf(P0, Tz, fmaf(P0, ta, Q0 * so)));
    T1 = fmaf(M1, T1, fmaf(P1, Tz, fmaf(P1, ta, Q1 * so)));
    T2 = fmaf(M2, T2, fmaf(P2, Tz, fmaf(P2, ta, Q2 * so)));
    T3 = fmaf(M3, T3, fmaf(P3, Tz, fmaf(P3, ta, Q3 * so)));
    T4 = fmaf(M4, T4, fmaf(P4, Tz, fmaf(P4, ta, Q4 * so)));
    float nz = tzn;
    if (tile0 && k < 47) nz = sTz[(k + 1) * LP + l];  // gt read BEFORE overwrite below
    sTz[k * LP + l] = tzn;                            // stage output
    Tz = nz;
  }
  if (ksteps > 0) {
    // [b][ER][8] layout: scattered store (fire-and-forget), coalesced read in k2sc
    float* ep = ws + E_OFF + ((size_t)b * ER + c) * 8;
    *(float4*)ep       = make_float4(Tz, T0, T1, T2);
    *(float2*)(ep + 4) = make_float2(T3, T4);
  }
  __syncthreads();

  // ---- Phase C: coalesced float4 out-tile write ----
  #pragma unroll
  for (int r = 0; r < 3; ++r) {
    int f  = threadIdx.x + 256 * r;       // 0..767
    int bl = f / 12, t4 = f - bl * 12;
    float4 v = make_float4(sTz[(4 * t4 + 0) * LP + bl], sTz[(4 * t4 + 1) * LP + bl],
                           sTz[(4 * t4 + 2) * LP + bl], sTz[(4 * t4 + 3) * LP + bl]);
    *(float4*)(out + (size_t)(b0 + bl) * TLEN + t0 + 4 * t4) = v;
  }
}

// ============ K2sc: fused scan + correction, one block per batch row ============
// Per block: rebuild A -> A^12 -> A^12^(2^k) in LDS (k0's exact MM sequence),
// V table; wave 0 runs the r11-proven shuffle scan for row b (e reads coalesced),
// stages X_c in LDS; then all 256 threads apply the superposition correction.
__global__ __launch_bounds__(256) void k2sc(
    const float* __restrict__ rcR, const float* __restrict__ rcC,
    const float* __restrict__ winR, const float* __restrict__ hvg,
    const float* __restrict__ ing, const float* __restrict__ dg,
    const float* __restrict__ aw, const float* __restrict__ ar,
    const float* __restrict__ zc,
    const float* __restrict__ e, float* __restrict__ out) {
  __shared__ float A0s[36], Ma[36], Mb[36], A4s[36], vbuf[2][8];
  __shared__ float sAp[7][40];     // A12^(2^k), k=0..6
  __shared__ float sV[6 * CLS];
  __shared__ float sXC[NCC][6];    // X_c, c=1..116 (slot 0 unused)
  int ln = threadIdx.x;
  Prm pp = make_prm(rcR, rcC, winR, hvg, ing, dg, aw, ar, zc);
  if (ln == 0) {
    #pragma unroll
    for (int i = 0; i < 36; ++i) A0s[i] = 0.f;
    A0s[0] = pp.AZ;
    #pragma unroll
    for (int j = 0; j < 5; ++j) {
      A0s[0 * 6 + 1 + j]       = pp.dtcz * pp.r[j];   // Kj
      A0s[(1 + j) * 6 + 0]     = pp.P[j];
      A0s[(1 + j) * 6 + 1 + j] = pp.M[j];
    }
  }
  __syncthreads();
  int i6 = ln / 6, j6 = ln % 6;
  bool act = ln < 36;
#define MM(DST, L, R) { if (act) { float s = 0.f; \
  for (int m = 0; m < 6; ++m) s = fmaf((L)[i6 * 6 + m], (R)[m * 6 + j6], s); \
  (DST)[ln] = s; } __syncthreads(); }
  MM(Mb, A0s, A0s);  // A^2
  MM(Ma, Mb, Mb);    // A^4
  if (act) A4s[ln] = Ma[ln];
  __syncthreads();
  MM(Mb, Ma, Ma);    // A^8
  MM(Ma, Mb, A4s);   // A^12  (k0's exact sequence)
  if (act) sAp[0][ln] = Ma[ln];
  __syncthreads();
  for (int k = 1; k < 7; ++k) {    // A12^2 .. A12^64 by squaring
    if (act) {
      float s = 0.f;
      #pragma unroll
      for (int m = 0; m < 6; ++m) s = fmaf(sAp[k - 1][i6 * 6 + m], sAp[k - 1][m * 6 + j6], s);
      sAp[k][ln] = s;
    }
    __syncthreads();
  }
  // V[k] = row0(A^(k+1)), k=0..CLS-1 (k0's exact vbuf iteration)
  if (ln < 6) vbuf[0][ln] = A0s[ln];
  __syncthreads();
  int cur = 0;
  for (int k = 0; k < CLS; ++k) {
    if (ln < 6) {
      sV[ln * CLS + k] = vbuf[cur][ln];
      float s = 0.f;
      #pragma unroll
      for (int m = 0; m < 6; ++m) s = fmaf(vbuf[cur][m], A0s[m * 6 + ln], s);
      vbuf[1 - cur][ln] = s;
    }
    __syncthreads();
    cur ^= 1;
  }

  // ---- wave 0: shuffle scan for row b (r11-proven math) ----
  int b = blockIdx.x;
  if (ln < 64) {
    int l = ln;
    const float* pA = e + ((size_t)b * ER + l) * 8;         // coalesced across lanes
    const float* pB = e + ((size_t)b * ER + 64 + l) * 8;    // rows 64..127 (padded)
    float yA[6], yB[6];
    { float4 q = *(const float4*)pA; float2 r = *(const float2*)(pA + 4);
      yA[0] = q.x; yA[1] = q.y; yA[2] = q.z; yA[3] = q.w; yA[4] = r.x; yA[5] = r.y; }
    { float4 q = *(const float4*)pB; float2 r = *(const float2*)(pB + 4);
      yB[0] = q.x; yB[1] = q.y; yB[2] = q.z; yB[3] = q.w; yB[4] = r.x; yB[5] = r.y; }
    #pragma unroll
    for (int k = 0; k < 6; ++k) {
      int d = 1 << k;
      int src = (l - d) & 63;
      float tA[6], tB[6];
      #pragma unroll
      for (int j = 0; j < 6; ++j) { tA[j] = __shfl(yA[j], src); tB[j] = __shfl(yB[j], src); }
      bool up = (l >= d);
      float sA[6], sB[6];
      #pragma unroll
      for (int j = 0; j < 6; ++j) { sA[j] = up ? tA[j] : 0.f; sB[j] = up ? tB[j] : tA[j]; }
      float nA[6], nB[6];
      #pragma unroll
      for (int i = 0; i < 6; ++i) {
        float uA = yA[i], uB = yB[i];
        #pragma unroll
        for (int m = 0; m < 6; ++m) {
          float a = sAp[k][i * 6 + m];
          uA = fmaf(a, sA[m], uA);
          uB = fmaf(a, sB[m], uB);
        }
        nA[i] = uA; nB[i] = uB;
      }
      #pragma unroll
      for (int i = 0; i < 6; ++i) { yA[i] = nA[i]; yB[i] = nB[i]; }
    }
    #pragma unroll
    for (int i = 0; i < 6; ++i) {      // y_{64+l} += A12^64 * y_l
      float uB = yB[i];
      #pragma unroll
      for (int m = 0; m < 6; ++m) uB = fmaf(sAp[6][i * 6 + m], yA[m], uB);
      yB[i] = uB;
    }
    // X_c = y_{c-1}: yA -> c = l+1 (1..64); yB -> c = 65+l (65..116, l<52)
    #pragma unroll
    for (int j = 0; j < 6; ++j) sXC[l + 1][j] = yA[j];
    if (l < 52) {
      #pragma unroll
      for (int j = 0; j < 6; ++j) sXC[65 + l][j] = yB[j];
    }
  }
  __syncthreads();

  // ---- correction: all 256 threads, float4 RMW on out row b ----
  for (int q = ln; q < (TLEN - CL0) / 4; q += 256) {
    int tt0 = q * 4;
    int c   = tt0 / CLS + 1;          // 1..116 (constant within the quad)
    int kk0 = tt0 - (c - 1) * CLS;    // 0,4,8
    float s0 = sXC[c][0], s1 = sXC[c][1], s2 = sXC[c][2];
    float s3 = sXC[c][3], s4 = sXC[c][4], s5 = sXC[c][5];
    float4* op = (float4*)(out + (size_t)b * TLEN + CL0 + tt0);
    float4 v = *op;
    float acc[4] = {v.x, v.y, v.z, v.w};
    #pragma unroll
    for (int ee = 0; ee < 4; ++ee) {
      int kk = kk0 + ee;
      float s = acc[ee];
      s = fmaf(sV[0 * CLS + kk], s0, s);
      s = fmaf(sV[1 * CLS + kk], s1, s);
      s = fmaf(sV[2 * CLS + kk], s2, s);
      s = fmaf(sV[3 * CLS + kk], s3, s);
      s = fmaf(sV[4 * CLS + kk], s4, s);
      s = fmaf(sV[5 * CLS + kk], s5, s);
      acc[ee] = s;
    }
    *op = make_float4(acc[0], acc[1], acc[2], acc[3]);
  }
}

// ============ Fallback: plain per-batch scan (if ws too small) ============
__global__ void k_fallback(const float* __restrict__ X,
    const float* __restrict__ rcR, const float* __restrict__ rcC,
    const float* __restrict__ winR, const float* __restrict__ hvg,
    const float* __restrict__ W1, const float* __restrict__ B1,
    const float* __restrict__ W2, const float* __restrict__ B2,
    const float* __restrict__ ing, const float* __restrict__ dg,
    const float* __restrict__ aw, const float* __restrict__ ar,
    const float* __restrict__ zc, float* __restrict__ out) {
  int b = blockIdx.x * 64 + threadIdx.x;
  if (b >= BATCH) return;
  Prm pp = make_prm(rcR, rcC, winR, hvg, ing, dg, aw, ar, zc);
  const float* xb = X + (size_t)b * (TLEN * 7);
  float Tz = xb[0];
  float tm = fmaf(0.7f, xb[0], 0.3f * xb[1]);
  float Tm[5] = {tm, tm, tm, tm, tm};
  for (int t = 0; t < TLEN; ++t) {
    const float* x = xb + t * 7;
    float ta = x[1], so = x[2], x3 = x[3], x4 = x[4], x5 = x[5], hv = x[6];
    float acc = B2[0];
    #pragma unroll
    for (int h = 0; h < 32; ++h) {
      float z = fmaf(W1[2 * h], x3, fmaf(W1[2 * h + 1], x4, B1[h]));
      acc = fmaf(W2[h], fmaxf(z, 0.f), acc);
    }
    float sch = __frcp_rn(1.f + __expf(-acc)) + x5;
    float q = fmaf(pp.cInt, sch, fmaf(pp.cHv, hv, pp.cDir * so));
    float u = fmaf(pp.dtczw, ta, pp.dtcz * q);
    float d = u;
    #pragma unroll
    for (int j = 0; j < 5; ++j) d = fmaf(pp.K[j], Tm[j], d);
    float tzn = fmaf(pp.AZ, Tz, d);
    #pragma unroll
    for (int j = 0; j < 5; ++j)
      Tm[j] = fmaf(pp.M[j], Tm[j], fmaf(pp.P[j], Tz, fmaf(pp.P[j], ta, pp.Q[j] * so)));
    out[(size_t)b * TLEN + t] = tzn;
    Tz = (t < 47) ? x[7] : tzn;
  }
}

extern "C" void kernel_launch(void* const* d_in, const int* in_sizes, int n_in,
                              void* d_out, int out_size, void* d_ws, size_t ws_size,
                              hipStream_t stream) {
  const float* X    = (const float*)d_in[0];
  const float* rcR  = (const float*)d_in[1];
  const float* rcC  = (const float*)d_in[2];
  const float* winR = (const float*)d_in[3];
  const float* hvg  = (const float*)d_in[4];
  const float* W1   = (const float*)d_in[5];
  const float* B1   = (const float*)d_in[6];
  const float* W2   = (const float*)d_in[7];
  const float* B2   = (const float*)d_in[8];
  const float* ing  = (const float*)d_in[9];
  const float* dg   = (const float*)d_in[10];
  const float* aw   = (const float*)d_in[11];
  const float* ar   = (const float*)d_in[12];
  const float* zc   = (const float*)d_in[13];
  float* out = (float*)d_out;
  float* ws  = (float*)d_ws;

  if (ws_size >= (size_t)WS_FLOATS * sizeof(float)) {
    k2a_scan<<<(BATCH / TB) * (TLEN / TT), 256, 0, stream>>>(
        X, rcR, rcC, winR, hvg, W1, B1, W2, B2, ing, dg, aw, ar, zc, out, ws);
    k2sc<<<BATCH, 256, 0, stream>>>(
        rcR, rcC, winR, hvg, ing, dg, aw, ar, zc, ws + E_OFF, out);
  } else {
    k_fallback<<<BATCH / 64, 64, 0, stream>>>(X, rcR, rcC, winR, hvg, W1, B1, W2, B2,
                                              ing, dg, aw, ar, zc, out);
  }
}

// Round 13
// 180.799 us; speedup vs baseline: 1.0856x; 1.0856x over previous
//
#include <hip/hip_runtime.h>
#include <math.h>

#define BATCH 2048
#define TLEN  1440
#define CL0   48     // chunk 0 length (>= ENC_LEN=48, covers teacher forcing)
#define CLS   12     // small-chunk length for t >= 48
#define NS    116    // (TLEN - CL0) / CLS
#define NCC   117    // total chunks = 1 + NS
#define ER    128    // e rows per batch (117 used; padded for lane reads)
#define TB    64     // b-tile
#define TT    48     // t-tile (= 4 small chunks = 1 forced chunk)
#define LP    65     // padded LDS row stride

// ---- workspace layout (float offsets) ----
// e: [BATCH][ER][8]  (k2a scatter-writes; k2sc reads lane-consecutive = coalesced)
#define E_OFF    0
#define AP_OFF   (E_OFF + BATCH*ER*8)     // [7][40]: A12^(2^k), k=0..6
#define VCOL_OFF (AP_OFF + 280)           // [6][CLS] row0 of A^(k+1), col-major
#define PRM_OFF  (VCOL_OFF + 96)          // derived params
#define WS_FLOATS (PRM_OFF + 32)

__device__ __forceinline__ float sp_precise(float x) { return log1pf(expf(x)); }

// ============ K0: params, A, A^12 (+powers), V rows ============
__global__ void k0_params(const float* __restrict__ rcR, const float* __restrict__ rcC,
                          const float* __restrict__ winR, const float* __restrict__ hvg,
                          const float* __restrict__ ing, const float* __restrict__ dg,
                          const float* __restrict__ aw, const float* __restrict__ ar,
                          const float* __restrict__ zc, float* __restrict__ ws) {
  __shared__ float A0s[36], Ma[36], Mb[36], A4s[36], vbuf[2][8];
  int ln = threadIdx.x;
  float r[5], cc[5];
  #pragma unroll
  for (int j = 0; j < 5; ++j) { r[j] = sp_precise(rcR[j]) * 0.1f; cc[j] = sp_precise(rcC[j]) * 1e-5f; }
  float w    = (sp_precise(winR[0]) + sp_precise(winR[1])) * 0.5f;
  float cz   = sp_precise(zc[0]) * 1e-5f;
  float aW   = sp_precise(aw[0]) * 0.5f, aR = sp_precise(ar[0]) * 0.5f;
  float dtcz = 900.f * cz;
  if (ln == 0) {
    float* prm = ws + PRM_OFF;
    float rsum = 0.f;
    for (int j = 0; j < 5; ++j) {
      float P = 900.f * r[j] * cc[j];
      prm[j]      = P;
      prm[5 + j]  = 1.f - 2.f * P;
      prm[10 + j] = 900.f * cc[j] * ((j < 4) ? aW : aR);
      prm[15 + j] = dtcz * r[j];
      rsum += r[j];
    }
    prm[20] = 1.f - dtcz * (w + rsum);  // AZ
    prm[21] = dtcz * w;                 // DTCZW
    prm[22] = dtcz;
    prm[23] = sp_precise(ing[0]) * 0.1f;  // c_int
    prm[24] = sp_precise(hvg[0]) * 0.1f;  // c_hvac
    prm[25] = sp_precise(dg[0])  * 0.5f;  // c_dir
    // Build A (state: [Tz, Tmid0..4])
    for (int i = 0; i < 36; ++i) A0s[i] = 0.f;
    A0s[0] = prm[20];
    for (int j = 0; j < 5; ++j) {
      A0s[0 * 6 + 1 + j]       = dtcz * r[j];          // Kj
      A0s[(1 + j) * 6 + 0]     = prm[j];               // Pj
      A0s[(1 + j) * 6 + 1 + j] = prm[5 + j];           // Mj
    }
  }
  __syncthreads();
  int i6 = ln / 6, j6 = ln % 6;
  bool act = ln < 36;
#define MM(DST, L, R) { if (act) { float s = 0.f; \
  for (int m = 0; m < 6; ++m) s = fmaf((L)[i6 * 6 + m], (R)[m * 6 + j6], s); \
  (DST)[ln] = s; } __syncthreads(); }
  MM(Mb, A0s, A0s);  // A^2
  MM(Ma, Mb, Mb);    // A^4
  if (act) A4s[ln] = Ma[ln];
  __syncthreads();
  MM(Mb, Ma, Ma);    // A^8
  MM(Ma, Mb, A4s);   // A^12
  if (act) ws[AP_OFF + 0 * 40 + ln] = Ma[ln];
  // A12^(2^k), k=1..6, by squaring (same fmaf sequence the r11 k2s used)
  MM(Mb, Ma, Ma);    // A12^2
  if (act) ws[AP_OFF + 1 * 40 + ln] = Mb[ln];
  MM(Ma, Mb, Mb);    // A12^4
  if (act) ws[AP_OFF + 2 * 40 + ln] = Ma[ln];
  MM(Mb, Ma, Ma);    // A12^8
  if (act) ws[AP_OFF + 3 * 40 + ln] = Mb[ln];
  MM(Ma, Mb, Mb);    // A12^16
  if (act) ws[AP_OFF + 4 * 40 + ln] = Ma[ln];
  MM(Mb, Ma, Ma);    // A12^32
  if (act) ws[AP_OFF + 5 * 40 + ln] = Mb[ln];
  MM(Ma, Mb, Mb);    // A12^64
  if (act) ws[AP_OFF + 6 * 40 + ln] = Ma[ln];
  // V[k] = row0(A^(k+1)), k = 0..CLS-1, stored column-major [j][k]
  if (ln < 6) vbuf[0][ln] = A0s[ln];
  __syncthreads();
  int cur = 0;
  for (int k = 0; k < CLS; ++k) {
    if (ln < 6) {
      ws[VCOL_OFF + ln * CLS + k] = vbuf[cur][ln];
      float s = 0.f;
      for (int m = 0; m < 6; ++m) s = fmaf(vbuf[cur][m], A0s[m * 6 + ln], s);
      vbuf[1 - cur][ln] = s;
    }
    __syncthreads();
    cur ^= 1;
  }
}

// ============ K2a: tiled fused MLP + scan (r11-proven, verbatim; prm from ws) ============
__global__ __launch_bounds__(256) void k2a_scan(const float* __restrict__ X,
    const float* __restrict__ W1, const float* __restrict__ B1,
    const float* __restrict__ W2, const float* __restrict__ B2,
    float* __restrict__ out, float* __restrict__ ws) {
  __shared__ float sTa[TT * LP], sSo[TT * LP], sU[TT * LP], sTz[TT * LP];
  int tile   = blockIdx.x;
  int tile_t = tile >> 5;          // 0..29
  int tile_b = tile & 31;          // 0..31
  int t0 = tile_t * TT, b0 = tile_b * TB;
  const float* prm = ws + PRM_OFF;
  float P0 = prm[0], P1 = prm[1], P2 = prm[2], P3 = prm[3], P4 = prm[4];
  float M0 = prm[5], M1 = prm[6], M2 = prm[7], M3 = prm[8], M4 = prm[9];
  float Q0 = prm[10], Q1 = prm[11], Q2 = prm[12], Q3 = prm[13], Q4 = prm[14];
  float K0 = prm[15], K1 = prm[16], K2 = prm[17], K3 = prm[18], K4 = prm[19];
  float AZ = prm[20];
  float dtczw = prm[21], dtcz = prm[22], cInt = prm[23], cHv = prm[24], cDir = prm[25];
  float b2v = B2[0];

  // ---- Phase A: 12 elems/thread, lane-consecutive in t (coalesced scalar loads) ----
  #pragma unroll 4
  for (int r = 0; r < (TB * TT) / 256; ++r) {
    int e  = threadIdx.x + 256 * r;
    int bl = e / TT;
    int tt = e - bl * TT;
    const float* x = X + ((size_t)(b0 + bl) * TLEN + (t0 + tt)) * 7;
    float x0 = x[0], ta = x[1], so = x[2], x3 = x[3], x4 = x[4], x5 = x[5], hv = x[6];
    float acc = b2v;
    #pragma unroll
    for (int h = 0; h < 32; ++h) {
      float z = fmaf(W1[2 * h], x3, fmaf(W1[2 * h + 1], x4, B1[h]));
      acc = fmaf(W2[h], fmaxf(z, 0.f), acc);
    }
    float sch = __frcp_rn(1.f + __expf(-acc)) + x5;
    float q = fmaf(cInt, sch, fmaf(cHv, hv, cDir * so));
    float u = fmaf(dtczw, ta, dtcz * q);
    sTa[tt * LP + bl] = ta;
    sSo[tt * LP + bl] = so;
    sU [tt * LP + bl] = u;
    sTz[tt * LP + bl] = x0;   // tz_gt staging (tile 0 forcing); overwritten by outputs
  }
  __syncthreads();

  // ---- Phase B: per-wave chunk scans from LDS ----
  int w = threadIdx.x >> 6, l = threadIdx.x & 63;
  int b = b0 + l;
  bool tile0 = (tile_t == 0);
  int c, kbeg, ksteps;
  if (tile0) { c = 0; kbeg = 0; ksteps = (w == 0) ? CL0 : 0; }
  else       { c = 1 + (tile_t - 1) * 4 + w; kbeg = w * CLS; ksteps = CLS; }
  float Tz = 0.f, T0 = 0.f, T1 = 0.f, T2 = 0.f, T3 = 0.f, T4 = 0.f;
  if (tile0) {
    float tz0 = sTz[l], ta0 = sTa[l];
    Tz = tz0;
    float tm = fmaf(0.7f, tz0, 0.3f * ta0);
    T0 = T1 = T2 = T3 = T4 = tm;
  }
  for (int k = kbeg; k < kbeg + ksteps; ++k) {
    float ta = sTa[k * LP + l], so = sSo[k * LP + l], u = sU[k * LP + l];
    float d = fmaf(K0, T0, u);
    d = fmaf(K1, T1, d); d = fmaf(K2, T2, d); d = fmaf(K3, T3, d); d = fmaf(K4, T4, d);
    float tzn = fmaf(AZ, Tz, d);
    T0 = fmaf(M0, T0, fmaf(P0, Tz, fmaf(P0, ta, Q0 * so)));
    T1 = fmaf(M1, T1, fmaf(P1, Tz, fmaf(P1, ta, Q1 * so)));
    T2 = fmaf(M2, T2, fmaf(P2, Tz, fmaf(P2, ta, Q2 * so)));
    T3 = fmaf(M3, T3, fmaf(P3, Tz, fmaf(P3, ta, Q3 * so)));
    T4 = fmaf(M4, T4, fmaf(P4, Tz, fmaf(P4, ta, Q4 * so)));
    float nz = tzn;
    if (tile0 && k < 47) nz = sTz[(k + 1) * LP + l];  // gt read BEFORE overwrite below
    sTz[k * LP + l] = tzn;                            // stage output
    Tz = nz;
  }
  if (ksteps > 0) {
    // [b][ER][8] layout: scattered store (fire-and-forget), coalesced read in k2sc
    float* ep = ws + E_OFF + ((size_t)b * ER + c) * 8;
    *(float4*)ep       = make_float4(Tz, T0, T1, T2);
    *(float2*)(ep + 4) = make_float2(T3, T4);
  }
  __syncthreads();

  // ---- Phase C: coalesced float4 out-tile write ----
  #pragma unroll
  for (int r = 0; r < 3; ++r) {
    int f  = threadIdx.x + 256 * r;       // 0..767
    int bl = f / 12, t4 = f - bl * 12;
    float4 v = make_float4(sTz[(4 * t4 + 0) * LP + bl], sTz[(4 * t4 + 1) * LP + bl],
                           sTz[(4 * t4 + 2) * LP + bl], sTz[(4 * t4 + 3) * LP + bl]);
    *(float4*)(out + (size_t)(b0 + bl) * TLEN + t0 + 4 * t4) = v;
  }
}

// ============ K2sc: fused scan + correction, one block per batch row ============
// Loads A12^(2^k) + V from ws (computed once in k0 — no per-block rebuild);
// wave 0 runs the r11-proven shuffle scan for row b (e reads lane-coalesced),
// stages X_c in LDS; all 256 threads apply the superposition correction.
__global__ __launch_bounds__(256) void k2sc(const float* __restrict__ e,
                                            float* __restrict__ out,
                                            const float* __restrict__ ws) {
  __shared__ float sAp[7][40];     // A12^(2^k), k=0..6
  __shared__ float sV[6 * CLS];
  __shared__ float sXC[NCC][6];    // X_c, c=1..116 (slot 0 unused)
  int ln = threadIdx.x;
  for (int i = ln; i < 7 * 40; i += 256) sAp[0][i] = ws[AP_OFF + i];  // pad slots unused
  for (int i = ln; i < 6 * CLS; i += 256) sV[i] = ws[VCOL_OFF + i];
  __syncthreads();

  int b = blockIdx.x;
  if (ln < 64) {
    int l = ln;
    const float* pA = e + ((size_t)b * ER + l) * 8;         // coalesced across lanes
    const float* pB = e + ((size_t)b * ER + 64 + l) * 8;    // rows 64..127 (padded)
    float yA[6], yB[6];
    { float4 q = *(const float4*)pA; float2 r = *(const float2*)(pA + 4);
      yA[0] = q.x; yA[1] = q.y; yA[2] = q.z; yA[3] = q.w; yA[4] = r.x; yA[5] = r.y; }
    { float4 q = *(const float4*)pB; float2 r = *(const float2*)(pB + 4);
      yB[0] = q.x; yB[1] = q.y; yB[2] = q.z; yB[3] = q.w; yB[4] = r.x; yB[5] = r.y; }
    #pragma unroll
    for (int k = 0; k < 6; ++k) {
      int d = 1 << k;
      int src = (l - d) & 63;
      float tA[6], tB[6];
      #pragma unroll
      for (int j = 0; j < 6; ++j) { tA[j] = __shfl(yA[j], src); tB[j] = __shfl(yB[j], src); }
      bool up = (l >= d);
      float sA[6], sB[6];
      #pragma unroll
      for (int j = 0; j < 6; ++j) { sA[j] = up ? tA[j] : 0.f; sB[j] = up ? tB[j] : tA[j]; }
      float nA[6], nB[6];
      #pragma unroll
      for (int i = 0; i < 6; ++i) {
        float uA = yA[i], uB = yB[i];
        #pragma unroll
        for (int m = 0; m < 6; ++m) {
          float a = sAp[k][i * 6 + m];
          uA = fmaf(a, sA[m], uA);
          uB = fmaf(a, sB[m], uB);
        }
        nA[i] = uA; nB[i] = uB;
      }
      #pragma unroll
      for (int i = 0; i < 6; ++i) { yA[i] = nA[i]; yB[i] = nB[i]; }
    }
    #pragma unroll
    for (int i = 0; i < 6; ++i) {      // y_{64+l} += A12^64 * y_l
      float uB = yB[i];
      #pragma unroll
      for (int m = 0; m < 6; ++m) uB = fmaf(sAp[6][i * 6 + m], yA[m], uB);
      yB[i] = uB;
    }
    // X_c = y_{c-1}: yA -> c = l+1 (1..64); yB -> c = 65+l (65..116, l<52)
    #pragma unroll
    for (int j = 0; j < 6; ++j) sXC[l + 1][j] = yA[j];
    if (l < 52) {
      #pragma unroll
      for (int j = 0; j < 6; ++j) sXC[65 + l][j] = yB[j];
    }
  }
  __syncthreads();

  // ---- correction: all 256 threads, float4 RMW on out row b ----
  for (int q = ln; q < (TLEN - CL0) / 4; q += 256) {
    int tt0 = q * 4;
    int c   = tt0 / CLS + 1;          // 1..116 (constant within the quad)
    int kk0 = tt0 - (c - 1) * CLS;    // 0,4,8
    float s0 = sXC[c][0], s1 = sXC[c][1], s2 = sXC[c][2];
    float s3 = sXC[c][3], s4 = sXC[c][4], s5 = sXC[c][5];
    float4* op = (float4*)(out + (size_t)b * TLEN + CL0 + tt0);
    float4 v = *op;
    float acc[4] = {v.x, v.y, v.z, v.w};
    #pragma unroll
    for (int ee = 0; ee < 4; ++ee) {
      int kk = kk0 + ee;
      float s = acc[ee];
      s = fmaf(sV[0 * CLS + kk], s0, s);
      s = fmaf(sV[1 * CLS + kk], s1, s);
      s = fmaf(sV[2 * CLS + kk], s2, s);
      s = fmaf(sV[3 * CLS + kk], s3, s);
      s = fmaf(sV[4 * CLS + kk], s4, s);
      s = fmaf(sV[5 * CLS + kk], s5, s);
      acc[ee] = s;
    }
    *op = make_float4(acc[0], acc[1], acc[2], acc[3]);
  }
}

// ============ Fallback: plain per-batch scan (if ws too small) ============
__global__ void k_fallback(const float* __restrict__ X,
    const float* __restrict__ rcR, const float* __restrict__ rcC,
    const float* __restrict__ winR, const float* __restrict__ hvg,
    const float* __restrict__ W1, const float* __restrict__ B1,
    const float* __restrict__ W2, const float* __restrict__ B2,
    const float* __restrict__ ing, const float* __restrict__ dg,
    const float* __restrict__ aw, const float* __restrict__ ar,
    const float* __restrict__ zc, float* __restrict__ out) {
  int b = blockIdx.x * 64 + threadIdx.x;
  if (b >= BATCH) return;
  float r[5], cc[5], P[5], M[5], Q[5], K[5];
  float rsum = 0.f;
  for (int j = 0; j < 5; ++j) { r[j] = sp_precise(rcR[j]) * 0.1f; cc[j] = sp_precise(rcC[j]) * 1e-5f; rsum += r[j]; }
  float w = (sp_precise(winR[0]) + sp_precise(winR[1])) * 0.5f;
  float cz = sp_precise(zc[0]) * 1e-5f;
  float aW = sp_precise(aw[0]) * 0.5f, aR = sp_precise(ar[0]) * 0.5f;
  float dtcz = 900.f * cz;
  for (int j = 0; j < 5; ++j) {
    P[j] = 900.f * r[j] * cc[j]; M[j] = 1.f - 2.f * P[j];
    Q[j] = 900.f * cc[j] * ((j < 4) ? aW : aR); K[j] = dtcz * r[j];
  }
  float AZ = 1.f - dtcz * (w + rsum), dtczw = dtcz * w;
  float cInt = sp_precise(ing[0]) * 0.1f, cHv = sp_precise(hvg[0]) * 0.1f, cDir = sp_precise(dg[0]) * 0.5f;
  const float* xb = X + (size_t)b * (TLEN * 7);
  float Tz = xb[0];
  float tm = fmaf(0.7f, xb[0], 0.3f * xb[1]);
  float Tm[5] = {tm, tm, tm, tm, tm};
  for (int t = 0; t < TLEN; ++t) {
    const float* x = xb + t * 7;
    float ta = x[1], so = x[2], x3 = x[3], x4 = x[4], x5 = x[5], hv = x[6];
    float acc = B2[0];
    #pragma unroll
    for (int h = 0; h < 32; ++h) {
      float z = fmaf(W1[2 * h], x3, fmaf(W1[2 * h + 1], x4, B1[h]));
      acc = fmaf(W2[h], fmaxf(z, 0.f), acc);
    }
    float sch = __frcp_rn(1.f + __expf(-acc)) + x5;
    float q = fmaf(cInt, sch, fmaf(cHv, hv, cDir * so));
    float u = fmaf(dtczw, ta, dtcz * q);
    float d = u;
    #pragma unroll
    for (int j = 0; j < 5; ++j) d = fmaf(K[j], Tm[j], d);
    float tzn = fmaf(AZ, Tz, d);
    #pragma unroll
    for (int j = 0; j < 5; ++j)
      Tm[j] = fmaf(M[j], Tm[j], fmaf(P[j], Tz, fmaf(P[j], ta, Q[j] * so)));
    out[(size_t)b * TLEN + t] = tzn;
    Tz = (t < 47) ? x[7] : tzn;
  }
}

extern "C" void kernel_launch(void* const* d_in, const int* in_sizes, int n_in,
                              void* d_out, int out_size, void* d_ws, size_t ws_size,
                              hipStream_t stream) {
  const float* X    = (const float*)d_in[0];
  const float* rcR  = (const float*)d_in[1];
  const float* rcC  = (const float*)d_in[2];
  const float* winR = (const float*)d_in[3];
  const float* hvg  = (const float*)d_in[4];
  const float* W1   = (const float*)d_in[5];
  const float* B1   = (const float*)d_in[6];
  const float* W2   = (const float*)d_in[7];
  const float* B2   = (const float*)d_in[8];
  const float* ing  = (const float*)d_in[9];
  const float* dg   = (const float*)d_in[10];
  const float* aw   = (const float*)d_in[11];
  const float* ar   = (const float*)d_in[12];
  const float* zc   = (const float*)d_in[13];
  float* out = (float*)d_out;
  float* ws  = (float*)d_ws;

  if (ws_size >= (size_t)WS_FLOATS * sizeof(float)) {
    k0_params<<<1, 64, 0, stream>>>(rcR, rcC, winR, hvg, ing, dg, aw, ar, zc, ws);
    k2a_scan<<<(BATCH / TB) * (TLEN / TT), 256, 0, stream>>>(X, W1, B1, W2, B2, out, ws);
    k2sc<<<BATCH, 256, 0, stream>>>(ws + E_OFF, out, ws);
  } else {
    k_fallback<<<BATCH / 64, 64, 0, stream>>>(X, rcR, rcC, winR, hvg, W1, B1, W2, B2,
                                              ing, dg, aw, ar, zc, out);
  }
}